// Round 2
// baseline (77.818 us; speedup 1.0000x reference)
//
#include <hip/hip_runtime.h>

// Problem constants
#define NSPLIT  100
#define MTREE   20
#define MAXLEAF 64
#define EMB     32
#define BATCH   4096
#define NTREES  2000

#define CPB     8                 // batch-chunks per split
#define BPB     (BATCH/CPB)       // 512 batches per block
#define THREADS 1024
#define GROUPS  (THREADS/8)       // 128 groups of 8 lanes
#define BPG     (BPB/GROUPS)      // 4 batches per group

// One block = one split x 512 batches. The split's 160 KB table is staged
// through 64 KiB of LDS in 3 phases (8/8/4 trees). LDS is chunk-major
// (lds4[c*512 + r]) so a gather's address is eb + J*64 + leaf: one VALU op,
// J*1024B folds into the ds_read offset immediate. Gather bank = leaf%8 ->
// only random same-residue collisions across the wave's 8 groups (~1.2x).
// Next phase's global loads are issued BEFORE the current gather phase so
// HBM/L3 latency hides under the LDS gather work (T14 split).
__global__ __launch_bounds__(THREADS) void leaf2emb_lds(
    const int* __restrict__ leaves,     // [BATCH, NTREES]
    const float* __restrict__ embed,    // [NSPLIT, MTREE*MAXLEAF, EMB]
    float* __restrict__ out)            // [BATCH, NSPLIT*EMB]
{
    __shared__ float4 lds4[8 * 512];    // 64 KiB

    // XCD-contiguous block swizzle (800 blocks = 8 XCDs x 100): each XCD's
    // blocks cover a contiguous range of (split, chunk) -> staging reads of a
    // split's table stay in that XCD's L2.
    const int bid   = blockIdx.x;
    const int orig  = (bid & 7) * (NSPLIT * CPB / 8) + (bid >> 3);
    const int s     = orig >> 3;        // / CPB
    const int chunk = orig & 7;         // % CPB

    const int tid = threadIdx.x;
    const int e4  = tid & 7;            // float4 slice of the 32-wide row
    const int g   = tid >> 3;           // group id = batch slot
    const int eb  = e4 << 9;            // this lane's chunk plane (e4*512)

    const float4* emb4 = (const float4*)embed + (size_t)s * 10240;

    const int b0 = chunk * BPB + g;
    const int b1 = b0 + GROUPS;
    const int b2 = b0 + 2 * GROUPS;
    const int b3 = b0 + 3 * GROUPS;
    const int* lv0 = leaves + b0 * NTREES + s * MTREE;
    const int* lv1 = leaves + b1 * NTREES + s * MTREE;
    const int* lv2 = leaves + b2 * NTREES + s * MTREE;
    const int* lv3 = leaves + b3 * NTREES + s * MTREE;

    float4 a0 = {0,0,0,0}, a1 = {0,0,0,0}, a2 = {0,0,0,0}, a3 = {0,0,0,0};

    // staging write slot: chunk f = tid + k*1024 -> r = (tid>>3)+k*128, c = tid&7
    const int wr = eb + g;

    // phase-0 staging loads (trees 0..7 = 4096 float4 chunks)
    float4 st0 = emb4[tid];
    float4 st1 = emb4[tid + 1024];
    float4 st2 = emb4[tid + 2048];
    float4 st3 = emb4[tid + 3072];

#define ACCUM(A, V) { A.x += (V).x; A.y += (V).y; A.z += (V).z; A.w += (V).w; }
#define GATH(A, J, LEAF) { float4 v_ = lds4[eb + (J)*64 + (LEAF)]; ACCUM(A, v_) }

#define GATHER8(P) { \
    int4 la0 = *(const int4*)(lv0 + (P)*8), lb0 = *(const int4*)(lv0 + (P)*8 + 4); \
    int4 la1 = *(const int4*)(lv1 + (P)*8), lb1 = *(const int4*)(lv1 + (P)*8 + 4); \
    int4 la2 = *(const int4*)(lv2 + (P)*8), lb2 = *(const int4*)(lv2 + (P)*8 + 4); \
    int4 la3 = *(const int4*)(lv3 + (P)*8), lb3 = *(const int4*)(lv3 + (P)*8 + 4); \
    GATH(a0,0,la0.x) GATH(a0,1,la0.y) GATH(a0,2,la0.z) GATH(a0,3,la0.w) \
    GATH(a0,4,lb0.x) GATH(a0,5,lb0.y) GATH(a0,6,lb0.z) GATH(a0,7,lb0.w) \
    GATH(a1,0,la1.x) GATH(a1,1,la1.y) GATH(a1,2,la1.z) GATH(a1,3,la1.w) \
    GATH(a1,4,lb1.x) GATH(a1,5,lb1.y) GATH(a1,6,lb1.z) GATH(a1,7,lb1.w) \
    GATH(a2,0,la2.x) GATH(a2,1,la2.y) GATH(a2,2,la2.z) GATH(a2,3,la2.w) \
    GATH(a2,4,lb2.x) GATH(a2,5,lb2.y) GATH(a2,6,lb2.z) GATH(a2,7,lb2.w) \
    GATH(a3,0,la3.x) GATH(a3,1,la3.y) GATH(a3,2,la3.z) GATH(a3,3,la3.w) \
    GATH(a3,4,lb3.x) GATH(a3,5,lb3.y) GATH(a3,6,lb3.z) GATH(a3,7,lb3.w) \
}

    // ---- phase 0: trees 0..7 ----
    lds4[wr] = st0; lds4[wr + 128] = st1; lds4[wr + 256] = st2; lds4[wr + 384] = st3;
    __syncthreads();
    // prefetch phase 1 (trees 8..15) while gathering phase 0
    st0 = emb4[4096 + tid];
    st1 = emb4[4096 + tid + 1024];
    st2 = emb4[4096 + tid + 2048];
    st3 = emb4[4096 + tid + 3072];
    GATHER8(0)
    __syncthreads();

    // ---- phase 1: trees 8..15 ----
    lds4[wr] = st0; lds4[wr + 128] = st1; lds4[wr + 256] = st2; lds4[wr + 384] = st3;
    __syncthreads();
    // prefetch phase 2 (trees 16..19, 2048 chunks)
    st0 = emb4[8192 + tid];
    st1 = emb4[8192 + tid + 1024];
    GATHER8(1)
    __syncthreads();

    // ---- phase 2: trees 16..19 ----
    lds4[wr] = st0; lds4[wr + 128] = st1;
    __syncthreads();
    {
        int4 la0 = *(const int4*)(lv0 + 16);
        int4 la1 = *(const int4*)(lv1 + 16);
        int4 la2 = *(const int4*)(lv2 + 16);
        int4 la3 = *(const int4*)(lv3 + 16);
        GATH(a0,0,la0.x) GATH(a0,1,la0.y) GATH(a0,2,la0.z) GATH(a0,3,la0.w)
        GATH(a1,0,la1.x) GATH(a1,1,la1.y) GATH(a1,2,la1.z) GATH(a1,3,la1.w)
        GATH(a2,0,la2.x) GATH(a2,1,la2.y) GATH(a2,2,la2.z) GATH(a2,3,la2.w)
        GATH(a3,0,la3.x) GATH(a3,1,la3.y) GATH(a3,2,la3.z) GATH(a3,3,la3.w)
    }

    float* ob = out + (size_t)s * EMB + (size_t)e4 * 4;
    *(float4*)(ob + (size_t)b0 * (NSPLIT * EMB)) = a0;
    *(float4*)(ob + (size_t)b1 * (NSPLIT * EMB)) = a1;
    *(float4*)(ob + (size_t)b2 * (NSPLIT * EMB)) = a2;
    *(float4*)(ob + (size_t)b3 * (NSPLIT * EMB)) = a3;
}

extern "C" void kernel_launch(void* const* d_in, const int* in_sizes, int n_in,
                              void* d_out, int out_size, void* d_ws, size_t ws_size,
                              hipStream_t stream) {
    const int* leaves  = (const int*)d_in[0];
    const float* embed = (const float*)d_in[1];
    float* out         = (float*)d_out;

    dim3 grid(NSPLIT * CPB);   // 800
    dim3 block(THREADS);       // 1024
    leaf2emb_lds<<<grid, block, 0, stream>>>(leaves, embed, out);
}

// Round 3
// 43.524 us; speedup vs baseline: 1.7879x; 1.7879x over previous
//
#include <hip/hip_runtime.h>

// Problem constants
#define NSPLIT  100
#define MTREE   20
#define MAXLEAF 64
#define EMB     32
#define NTREES  2000
#define BATCH   4096

#define THREADS 1024
#define CPB     8                  // batch-chunks per split
#define BPB     (BATCH/CPB)        // 512 batches per block
#define GROUPS  (THREADS/8)        // 128 groups (one per batch slot)

#define PHASE_F4 2048              // 4 trees * 64 leaves * 8 float4 = 32 KiB

// One block = one split x 512 batches. Table staged through 2 x 32 KiB LDS
// buffers, 5 phases of 4 trees, ROW-MAJOR: buf[(t*64+leaf)*8 + e4].
// Gather: a group's 8 lanes read one contiguous 128B row -> full 32-bank
// sweep, conflict-free (round-2's chunk-major layout was an 8-way conflict:
// 2.47e7 conflict cycles). Row-major == linear in global order, so staging
// uses global_load_lds width-16 DMA (wave-uniform dest + lane*16).
// Next phase's leaf loads + DMA are issued BEFORE the current gather; the
// per-phase __syncthreads() drains vmcnt (T14-style overlap).
__device__ __forceinline__ void stage_dma(const float4* gsrc, void* lbase) {
    __builtin_amdgcn_global_load_lds(
        (const __attribute__((address_space(1))) void*)gsrc,
        (__attribute__((address_space(3))) void*)lbase, 16, 0, 0);
}

__global__ __launch_bounds__(THREADS) void leaf2emb_v3(
    const int* __restrict__ leaves,     // [BATCH, NTREES]
    const float* __restrict__ embed,    // [NSPLIT, MTREE*MAXLEAF, EMB]
    float* __restrict__ out)            // [BATCH, NSPLIT*EMB]
{
    __shared__ float4 buf[2][PHASE_F4];   // 2 x 32 KiB

    // XCD-contiguous swizzle: one split's 8 chunk-blocks land on one XCD.
    const int bid   = blockIdx.x;
    const int orig  = (bid & 7) * (NSPLIT * CPB / 8) + (bid >> 3);
    const int s     = orig >> 3;
    const int chunk = orig & 7;

    const int tid  = threadIdx.x;
    const int e4   = tid & 7;          // float4 slice of the 32-wide row
    const int g    = tid >> 3;         // batch slot within chunk
    const int w    = tid >> 6;         // wave id (uniform)
    const int lane = tid & 63;

    const float4* emb4 = (const float4*)embed + (size_t)s * 10240;

    const int b0 = chunk * BPB + g;
    const int* lv0 = leaves + (size_t)b0 * NTREES + s * MTREE;
    const int* lv1 = lv0 + (size_t)GROUPS * NTREES;
    const int* lv2 = lv1 + (size_t)GROUPS * NTREES;
    const int* lv3 = lv2 + (size_t)GROUPS * NTREES;

    float4 a0 = {0,0,0,0}, a1 = {0,0,0,0}, a2 = {0,0,0,0}, a3 = {0,0,0,0};

    // Stage phase P (trees 4P..4P+3) into buf[NB]: 2048 float4, 2 DMA/wave.
#define STAGE(P, NB) {                                                  \
        const float4* gs_ = emb4 + (P)*PHASE_F4 + w*64 + lane;          \
        char* lb_ = (char*)&buf[NB][w*64];                              \
        stage_dma(gs_,        lb_);                                     \
        stage_dma(gs_ + 1024, lb_ + 16384);                             \
    }

#define GATH(A, NB, J, LEAF) {                                          \
        float4 v_ = buf[NB][(J)*512 + (LEAF)*8 + e4];                   \
        A.x += v_.x; A.y += v_.y; A.z += v_.z; A.w += v_.w; }

#define GATHER4(NB, C0, C1, C2, C3) {                                   \
        GATH(a0,NB,0,C0.x) GATH(a0,NB,1,C0.y) GATH(a0,NB,2,C0.z) GATH(a0,NB,3,C0.w) \
        GATH(a1,NB,0,C1.x) GATH(a1,NB,1,C1.y) GATH(a1,NB,2,C1.z) GATH(a1,NB,3,C1.w) \
        GATH(a2,NB,0,C2.x) GATH(a2,NB,1,C2.y) GATH(a2,NB,2,C2.z) GATH(a2,NB,3,C2.w) \
        GATH(a3,NB,0,C3.x) GATH(a3,NB,1,C3.y) GATH(a3,NB,2,C3.z) GATH(a3,NB,3,C3.w) }

    // ---- prologue: leaves for phase 0 + DMA phase 0 into buf0 ----
    int4 c0 = *(const int4*)(lv0);
    int4 c1 = *(const int4*)(lv1);
    int4 c2 = *(const int4*)(lv2);
    int4 c3 = *(const int4*)(lv3);
    STAGE(0, 0)
    __syncthreads();

    // ---- phase 0 ----
    int4 n0 = *(const int4*)(lv0 + 4);
    int4 n1 = *(const int4*)(lv1 + 4);
    int4 n2 = *(const int4*)(lv2 + 4);
    int4 n3 = *(const int4*)(lv3 + 4);
    STAGE(1, 1)
    GATHER4(0, c0, c1, c2, c3)
    __syncthreads();
    c0 = n0; c1 = n1; c2 = n2; c3 = n3;

    // ---- phase 1 ----
    n0 = *(const int4*)(lv0 + 8);
    n1 = *(const int4*)(lv1 + 8);
    n2 = *(const int4*)(lv2 + 8);
    n3 = *(const int4*)(lv3 + 8);
    STAGE(2, 0)
    GATHER4(1, c0, c1, c2, c3)
    __syncthreads();
    c0 = n0; c1 = n1; c2 = n2; c3 = n3;

    // ---- phase 2 ----
    n0 = *(const int4*)(lv0 + 12);
    n1 = *(const int4*)(lv1 + 12);
    n2 = *(const int4*)(lv2 + 12);
    n3 = *(const int4*)(lv3 + 12);
    STAGE(3, 1)
    GATHER4(0, c0, c1, c2, c3)
    __syncthreads();
    c0 = n0; c1 = n1; c2 = n2; c3 = n3;

    // ---- phase 3 ----
    n0 = *(const int4*)(lv0 + 16);
    n1 = *(const int4*)(lv1 + 16);
    n2 = *(const int4*)(lv2 + 16);
    n3 = *(const int4*)(lv3 + 16);
    STAGE(4, 0)
    GATHER4(1, c0, c1, c2, c3)
    __syncthreads();
    c0 = n0; c1 = n1; c2 = n2; c3 = n3;

    // ---- phase 4 (no staging) ----
    GATHER4(0, c0, c1, c2, c3)

    // out[b, s*EMB + e4*4]; 8 lanes x 16B = contiguous 128B per batch
    float* ob = out + (size_t)s * EMB + (size_t)e4 * 4;
    *(float4*)(ob + (size_t)b0 * (NSPLIT * EMB))                    = a0;
    *(float4*)(ob + (size_t)(b0 + GROUPS) * (NSPLIT * EMB))         = a1;
    *(float4*)(ob + (size_t)(b0 + 2 * GROUPS) * (NSPLIT * EMB))     = a2;
    *(float4*)(ob + (size_t)(b0 + 3 * GROUPS) * (NSPLIT * EMB))     = a3;

#undef STAGE
#undef GATH
#undef GATHER4
}

extern "C" void kernel_launch(void* const* d_in, const int* in_sizes, int n_in,
                              void* d_out, int out_size, void* d_ws, size_t ws_size,
                              hipStream_t stream) {
    const int* leaves  = (const int*)d_in[0];
    const float* embed = (const float*)d_in[1];
    float* out         = (float*)d_out;

    dim3 grid(NSPLIT * CPB);   // 800
    dim3 block(THREADS);       // 1024
    leaf2emb_v3<<<grid, block, 0, stream>>>(leaves, embed, out);
}

// Round 4
// 40.798 us; speedup vs baseline: 1.9074x; 1.0668x over previous
//
#include <hip/hip_runtime.h>

// Problem constants
#define NSPLIT  100
#define MTREE   20
#define MAXLEAF 64
#define EMB     32
#define NTREES  2000
#define BATCH   4096

#define THREADS 1024
#define CPB     8                    // batch-chunks per split
#define BPB     (BATCH/CPB)          // 512 batches per block
#define GROUPS  (THREADS/8)          // 128 groups (8 lanes each)
#define TAB_F4  (MTREE*MAXLEAF*8)    // 10240 float4 = whole split table
#define LDS_BYTES (TAB_F4*16)        // 163840 = 160 KiB

// One block = one split x 512 batches. The ENTIRE 160 KiB table is staged
// into dynamic LDS once (10 global_load_lds DMAs per lane), then ONE
// __syncthreads, then 80 gathers/thread run with zero further barriers —
// round-3's 5 barrier+vmcnt(0) drains were the ~60% port-idle gap.
// Layout row-major: tab[(t*64+leaf)*8 + e4] -> a group's 8 lanes read one
// contiguous 128B row (full 32-bank sweep, conflict-free). Leaf int4 loads
// are prefetched one 4-tree chunk ahead so global latency hides under LDS.
__device__ __forceinline__ void stage_dma(const float4* gsrc, void* lbase) {
    __builtin_amdgcn_global_load_lds(
        (const __attribute__((address_space(1))) void*)gsrc,
        (__attribute__((address_space(3))) void*)lbase, 16, 0, 0);
}

__global__ __launch_bounds__(THREADS) void leaf2emb_v4(
    const int* __restrict__ leaves,     // [BATCH, NTREES]
    const float* __restrict__ embed,    // [NSPLIT, MTREE*MAXLEAF, EMB]
    float* __restrict__ out)            // [BATCH, NSPLIT*EMB]
{
    extern __shared__ float4 tab[];     // 10240 float4 = 160 KiB

    // XCD-contiguous swizzle (800 = 8 XCDs x 100): a split's 8 chunk-blocks
    // share an XCD so the 160 KB staging reads stay L2-local.
    const int bid   = blockIdx.x;
    const int orig  = (bid & 7) * (NSPLIT * CPB / 8) + (bid >> 3);
    const int s     = orig >> 3;
    const int chunk = orig & 7;

    const int tid  = threadIdx.x;
    const int e4   = tid & 7;           // float4 slice of the 32-wide row
    const int g    = tid >> 3;          // batch slot
    const int w    = tid >> 6;          // wave id
    const int lane = tid & 63;

    const float4* emb4 = (const float4*)embed + (size_t)s * TAB_F4;

    // ---- stage whole table: wave w owns float4 [w*640, w*640+640) ----
    {
        const float4* gs = emb4 + w * 640 + lane;
        char* lb = (char*)(tab + w * 640);
#pragma unroll
        for (int k = 0; k < 10; ++k)
            stage_dma(gs + k * 64, lb + k * 1024);
    }

    const int b0 = chunk * BPB + g;
    const int* lv0 = leaves + (size_t)b0 * NTREES + s * MTREE;
    const int* lv1 = lv0 + (size_t)GROUPS * NTREES;
    const int* lv2 = lv1 + (size_t)GROUPS * NTREES;
    const int* lv3 = lv2 + (size_t)GROUPS * NTREES;

    // leaves for chunk 0 (trees 0..3) in flight during staging
    int4 c0 = *(const int4*)(lv0);
    int4 c1 = *(const int4*)(lv1);
    int4 c2 = *(const int4*)(lv2);
    int4 c3 = *(const int4*)(lv3);

    float4 a0 = {0,0,0,0}, a1 = {0,0,0,0}, a2 = {0,0,0,0}, a3 = {0,0,0,0};

    __syncthreads();   // drains staging DMA (and leaf loads)

#define GATH(A, BC, J, LEAF) {                                          \
        float4 v_ = (BC)[(J)*512 + (LEAF)*8];                           \
        A.x += v_.x; A.y += v_.y; A.z += v_.z; A.w += v_.w; }

#define GATHER4(BC, C0, C1, C2, C3) {                                   \
        GATH(a0,BC,0,(C0).x) GATH(a0,BC,1,(C0).y) GATH(a0,BC,2,(C0).z) GATH(a0,BC,3,(C0).w) \
        GATH(a1,BC,0,(C1).x) GATH(a1,BC,1,(C1).y) GATH(a1,BC,2,(C1).z) GATH(a1,BC,3,(C1).w) \
        GATH(a2,BC,0,(C2).x) GATH(a2,BC,1,(C2).y) GATH(a2,BC,2,(C2).z) GATH(a2,BC,3,(C2).w) \
        GATH(a3,BC,0,(C3).x) GATH(a3,BC,1,(C3).y) GATH(a3,BC,2,(C3).z) GATH(a3,BC,3,(C3).w) }

    // ---- chunk 0 (trees 0..3), prefetch chunk 1 leaves ----
    int4 n0 = *(const int4*)(lv0 + 4);
    int4 n1 = *(const int4*)(lv1 + 4);
    int4 n2 = *(const int4*)(lv2 + 4);
    int4 n3 = *(const int4*)(lv3 + 4);
    { const float4* bc = tab + e4;           GATHER4(bc, c0, c1, c2, c3) }
    c0 = n0; c1 = n1; c2 = n2; c3 = n3;

    // ---- chunk 1 (trees 4..7) ----
    n0 = *(const int4*)(lv0 + 8);
    n1 = *(const int4*)(lv1 + 8);
    n2 = *(const int4*)(lv2 + 8);
    n3 = *(const int4*)(lv3 + 8);
    { const float4* bc = tab + 2048 + e4;    GATHER4(bc, c0, c1, c2, c3) }
    c0 = n0; c1 = n1; c2 = n2; c3 = n3;

    // ---- chunk 2 (trees 8..11) ----
    n0 = *(const int4*)(lv0 + 12);
    n1 = *(const int4*)(lv1 + 12);
    n2 = *(const int4*)(lv2 + 12);
    n3 = *(const int4*)(lv3 + 12);
    { const float4* bc = tab + 4096 + e4;    GATHER4(bc, c0, c1, c2, c3) }
    c0 = n0; c1 = n1; c2 = n2; c3 = n3;

    // ---- chunk 3 (trees 12..15) ----
    n0 = *(const int4*)(lv0 + 16);
    n1 = *(const int4*)(lv1 + 16);
    n2 = *(const int4*)(lv2 + 16);
    n3 = *(const int4*)(lv3 + 16);
    { const float4* bc = tab + 6144 + e4;    GATHER4(bc, c0, c1, c2, c3) }
    c0 = n0; c1 = n1; c2 = n2; c3 = n3;

    // ---- chunk 4 (trees 16..19) ----
    { const float4* bc = tab + 8192 + e4;    GATHER4(bc, c0, c1, c2, c3) }

#undef GATH
#undef GATHER4

    // out[b, s*EMB + e4*4]: 8 lanes x 16B = contiguous 128B per batch
    float* ob = out + (size_t)s * EMB + (size_t)e4 * 4;
    *(float4*)(ob + (size_t)b0 * (NSPLIT * EMB))                = a0;
    *(float4*)(ob + (size_t)(b0 + GROUPS) * (NSPLIT * EMB))     = a1;
    *(float4*)(ob + (size_t)(b0 + 2 * GROUPS) * (NSPLIT * EMB)) = a2;
    *(float4*)(ob + (size_t)(b0 + 3 * GROUPS) * (NSPLIT * EMB)) = a3;
}

extern "C" void kernel_launch(void* const* d_in, const int* in_sizes, int n_in,
                              void* d_out, int out_size, void* d_ws, size_t ws_size,
                              hipStream_t stream) {
    const int* leaves  = (const int*)d_in[0];
    const float* embed = (const float*)d_in[1];
    float* out         = (float*)d_out;

    // Allow 160 KiB dynamic LDS (AITER/HK-style full-CU workgroup LDS).
    // Host-side attribute set: idempotent, deterministic, graph-capture-safe
    // (not a stream op, no alloc/sync).
    (void)hipFuncSetAttribute((const void*)leaf2emb_v4,
                              hipFuncAttributeMaxDynamicSharedMemorySize,
                              LDS_BYTES);

    dim3 grid(NSPLIT * CPB);   // 800
    dim3 block(THREADS);       // 1024
    leaf2emb_v4<<<grid, block, LDS_BYTES, stream>>>(leaves, embed, out);
}